// Round 8
// baseline (329.718 us; speedup 1.0000x reference)
//
#include <hip/hip_runtime.h>
#include <math.h>
#include <stdint.h>

#define NND 20000
#define DIMK 512
#define NE  320000

typedef __attribute__((ext_vector_type(8))) short short8;
typedef __attribute__((ext_vector_type(4))) float floatx4;
typedef __attribute__((ext_vector_type(2))) float float2v;

__device__ inline float bf2f(unsigned short h) {
    unsigned int u = ((unsigned int)h) << 16;
    return __uint_as_float(u);
}
__device__ inline unsigned short f2bf(float f) {
    unsigned int u = __float_as_uint(f);
    unsigned int r = (u + 0x7fffu + ((u >> 16) & 1u)) >> 16;
    return (unsigned short)r;
}

__device__ __forceinline__ void gld_lds16(const unsigned short* g, unsigned short* l) {
    __builtin_amdgcn_global_load_lds(
        (const __attribute__((address_space(1))) void*)g,
        (__attribute__((address_space(3))) void*)l,
        16, 0, 0);
}

// ---------------- fused pre-pass: logmap + W cvt + bias + dst histogram -------
__global__ __launch_bounds__(256) void k_pre(const float* __restrict__ x,
                                             const float* __restrict__ Wq,
                                             const float* __restrict__ Wk,
                                             const float* __restrict__ Wv,
                                             const float* __restrict__ Wo,
                                             const float* __restrict__ bq,
                                             const float* __restrict__ bk,
                                             const float* __restrict__ bv,
                                             const int* __restrict__ dst,
                                             int* __restrict__ counts,
                                             unsigned short* __restrict__ t,
                                             unsigned short* __restrict__ Wqkv,
                                             unsigned short* __restrict__ Wob,
                                             float* __restrict__ biasf,
                                             float scale_q) {
    int blk = blockIdx.x, tid = threadIdx.x;
    if (blk < 5000) {
        int row = blk * 4 + (tid >> 6);
        int lane = tid & 63;
        const floatx4* xp = (const floatx4*)(x + (size_t)row * DIMK + lane * 8);
        floatx4 x0 = xp[0], x1 = xp[1];
        float ss = 0.f;
#pragma unroll
        for (int i = 0; i < 4; i++) { ss += x0[i] * x0[i]; ss += x1[i] * x1[i]; }
#pragma unroll
        for (int off = 32; off >= 1; off >>= 1) ss += __shfl_xor(ss, off, 64);
        float n  = sqrtf(ss);
        float nc = fminf(fmaxf(n, 1e-7f), 1.0f - 1e-6f);
        float fac = atanhf(nc) / nc;
        union { short8 v; unsigned short u[8]; } o;
#pragma unroll
        for (int i = 0; i < 4; i++) { o.u[i] = f2bf(fac * x0[i]); o.u[4 + i] = f2bf(fac * x1[i]); }
        *(short8*)(t + (size_t)row * DIMK + lane * 8) = o.v;
    } else if (blk < 6024) {
        int i = (blk - 5000) * 256 + tid;           // 0 .. 4*65536
        int m = i >> 16, j = i & 65535;
        const float* in; unsigned short* out; float sc = 1.0f;
        if (m == 0)      { in = Wq; out = Wqkv;               sc = scale_q; }
        else if (m == 1) { in = Wk; out = Wqkv + 512 * DIMK;  sc = 16.0f; }
        else if (m == 2) { in = Wv; out = Wqkv + 1024 * DIMK; sc = 16.0f; }
        else             { in = Wo; out = Wob; }
        floatx4 f = *(const floatx4*)(in + (size_t)j * 4);
        union { unsigned long long d; unsigned short u[4]; } o;
#pragma unroll
        for (int q = 0; q < 4; q++) o.u[q] = f2bf(f[q] * sc);
        *(unsigned long long*)(out + (size_t)j * 4) = o.d;
    } else if (blk < 6030) {
        int i = (blk - 6024) * 256 + tid;           // 0..1535
        if (i < 512) biasf[i] = bq[i] * scale_q;
        else if (i < 1024) biasf[i] = bk[i - 512] * 16.0f;
        else if (i < 1536) biasf[i] = bv[i - 1024] * 16.0f;
    } else {
        int e = (blk - 6030) * 256 + tid;
        if (e < NE) atomicAdd(&counts[dst[e]], 1);
    }
}

// ---------------- GEMM: A via LDS dbuf, B direct global->VGPR w/ prefetch -----
// C[M x Ncols] = A[M x 512] @ B[Ncols x 512]^T + bias. Block tile 128x128, BK=32.
// B (weights, <=1.5MB) is L2-resident: each wave loads its own fragments from
// global with a 1-iteration register prefetch -> halves LDS traffic vs staging.
// qkv mode (out_f==0): nt 0-3 -> q bf16; nt 4-7 -> k fp8 (x16); nt 8-11 -> v fp8 (x16)
//   k/v interleave into kv8 rows: [k(512B) | v(512B)], stride 1024.
__global__ __launch_bounds__(256) void k_gemm(const unsigned short* __restrict__ A,
                                              const unsigned short* __restrict__ B,
                                              const float* __restrict__ biasf,
                                              unsigned short* __restrict__ out_q,
                                              unsigned char*  __restrict__ out_kv8,
                                              float* __restrict__ out_f,
                                              int M, int MT, int NT, int Ncols) {
    __shared__ unsigned short smem[8192];       // A dbuf: 2 x 4096 shorts (8KB each)
    int b = blockIdx.x;
    int xcd = b & 7, i = b >> 3;
    int nt = i % NT, mt = (i / NT) * 8 + xcd;
    if (mt >= MT) return;
    int m0 = mt * 128, n0 = nt * 128;
    int tid = threadIdx.x, wv = tid >> 6, ln = tid & 63;
    int lr = ln & 15, qd = ln >> 4;
    int mh = wv >> 1, nh = wv & 1;

    floatx4 acc[4][4] = {};
    int srow = wv * 16 + (ln >> 2);
    int scol = (ln & 3) * 8;

    const unsigned short* Bbase = B + (size_t)(n0 + nh * 64 + lr) * DIMK + qd * 8;

    // prologue: stage A k-block 0 into buffer 0; prefetch B frags for kb=0
#pragma unroll
    for (int p = 0; p < 2; p++) {
        int ar = m0 + p * 64 + srow; if (ar > M - 1) ar = M - 1;
        gld_lds16(A + (size_t)ar * DIMK + scol, smem + (p * 64 + wv * 16) * 32);
    }
    short8 bpre[4];
#pragma unroll
    for (int ni = 0; ni < 4; ni++)
        bpre[ni] = *(const short8*)(Bbase + (size_t)ni * 16 * DIMK);

    for (int it = 0; it < 16; it++) {
        int cur = it & 1, nxt = cur ^ 1;
        __syncthreads();                        // A buf[cur] ready; nxt free
        if (it + 1 < 16) {
            int kb = (it + 1) * 32;
            unsigned short* Ab = smem + nxt * 4096;
#pragma unroll
            for (int p = 0; p < 2; p++) {
                int ar = m0 + p * 64 + srow; if (ar > M - 1) ar = M - 1;
                gld_lds16(A + (size_t)ar * DIMK + kb + scol, Ab + (p * 64 + wv * 16) * 32);
            }
        }
        short8 bfr[4];
#pragma unroll
        for (int ni = 0; ni < 4; ni++) bfr[ni] = bpre[ni];
        if (it + 1 < 16) {
            int kb = (it + 1) * 32;
#pragma unroll
            for (int ni = 0; ni < 4; ni++)
                bpre[ni] = *(const short8*)(Bbase + (size_t)ni * 16 * DIMK + kb);
        }
        const unsigned short* Ac = smem + cur * 4096;
        short8 af[4];
#pragma unroll
        for (int mi = 0; mi < 4; mi++)
            af[mi] = *(const short8*)(Ac + (mh * 64 + mi * 16 + lr) * 32 + qd * 8);
#pragma unroll
        for (int mi = 0; mi < 4; mi++)
#pragma unroll
            for (int ni = 0; ni < 4; ni++)
                acc[mi][ni] = __builtin_amdgcn_mfma_f32_16x16x32_bf16(af[mi], bfr[ni], acc[mi][ni], 0, 0, 0);
    }

    float bb[4];
#pragma unroll
    for (int ni = 0; ni < 4; ni++) bb[ni] = biasf[n0 + nh * 64 + ni * 16 + lr];

    if (!out_f) {
        int region = nt >> 2;          // 0=q bf16, 1=k fp8, 2=v fp8
        int col0 = (nt & 3) * 128;
        unsigned short* cs = smem;     // 32x128 shorts = 4096, fits
#pragma unroll
        for (int g = 0; g < 4; g++) {
            __syncthreads();
            if (mh == (g >> 1)) {
                int miB = (g & 1) * 2;
#pragma unroll
                for (int m2 = 0; m2 < 2; m2++) {
                    int mi = miB + m2;
                    int lrow = mi * 16 + qd * 4 - (g & 1) * 32;
#pragma unroll
                    for (int ni = 0; ni < 4; ni++) {
                        int col = nh * 64 + ni * 16 + lr;
#pragma unroll
                        for (int r = 0; r < 4; r++)
                            cs[(lrow + r) * 128 + col] = f2bf(acc[mi][ni][r] + bb[ni]);
                    }
                }
            }
            __syncthreads();
#pragma unroll
            for (int itr = 0; itr < 2; itr++) {
                int slot = itr * 256 + tid;
                int row = slot >> 4, cg = slot & 15;
                int gm = m0 + g * 32 + row;
                if (gm < M) {
                    short8 vv = *(const short8*)(cs + row * 128 + cg * 8);
                    if (region == 0) {
                        *(short8*)(out_q + (size_t)gm * 512 + col0 + cg * 8) = vv;
                    } else {
                        union { short8 v; unsigned short u[8]; } pk; pk.v = vv;
                        int w0 = 0, w1 = 0;
                        w0 = __builtin_amdgcn_cvt_pk_fp8_f32(bf2f(pk.u[0]), bf2f(pk.u[1]), w0, false);
                        w0 = __builtin_amdgcn_cvt_pk_fp8_f32(bf2f(pk.u[2]), bf2f(pk.u[3]), w0, true);
                        w1 = __builtin_amdgcn_cvt_pk_fp8_f32(bf2f(pk.u[4]), bf2f(pk.u[5]), w1, false);
                        w1 = __builtin_amdgcn_cvt_pk_fp8_f32(bf2f(pk.u[6]), bf2f(pk.u[7]), w1, true);
                        uint2 o; o.x = (unsigned int)w0; o.y = (unsigned int)w1;
                        size_t off = (size_t)gm * 1024 + (region == 2 ? 512 : 0) + col0 + cg * 8;
                        *(uint2*)(out_kv8 + off) = o;
                    }
                }
            }
        }
    } else {
#pragma unroll
        for (int ni = 0; ni < 4; ni++) {
            int gn = n0 + nh * 64 + ni * 16 + lr;
#pragma unroll
            for (int mi = 0; mi < 4; mi++) {
                int gm0 = m0 + mh * 64 + mi * 16 + qd * 4;
#pragma unroll
                for (int r = 0; r < 4; r++) {
                    int gm = gm0 + r;
                    if (gm < M) out_f[(size_t)gm * Ncols + gn] = acc[mi][ni][r] + bb[ni];
                }
            }
        }
    }
}

// ---------------- CSR scan + scatter ------------------------------------------
__global__ __launch_bounds__(1024) void k_scan(const int* __restrict__ counts,
                                               int* __restrict__ offsets,
                                               int* __restrict__ pos) {
    const int C = 20;
    __shared__ int wsum[16];
    __shared__ int wpre[16];
    int tid = threadIdx.x, lane = tid & 63, w = tid >> 6;
    int local[C];
    int run = 0;
#pragma unroll
    for (int i = 0; i < C; i++) {
        int idx = tid * C + i;
        int c = (idx < NND) ? counts[idx] : 0;
        local[i] = run; run += c;
    }
    int v = run;
#pragma unroll
    for (int off = 1; off < 64; off <<= 1) {
        int u = __shfl_up(v, off, 64);
        if (lane >= off) v += u;
    }
    if (lane == 63) wsum[w] = v;
    __syncthreads();
    if (tid == 0) { int acc = 0; for (int i = 0; i < 16; i++) { wpre[i] = acc; acc += wsum[i]; } }
    __syncthreads();
    int texcl = wpre[w] + (v - run);
#pragma unroll
    for (int i = 0; i < C; i++) {
        int idx = tid * C + i;
        if (idx < NND) { int o = texcl + local[i]; offsets[idx] = o; pos[idx] = o; }
    }
    if (tid == 1023) offsets[NND] = texcl + run;
}

__global__ void k_scatter(const int* __restrict__ dst, const int* __restrict__ src,
                          int* __restrict__ pos, int* __restrict__ ssrc) {
    int e = blockIdx.x * 256 + threadIdx.x;
    if (e < NE) { int p = atomicAdd(&pos[dst[e]], 1); ssrc[p] = src[e]; }
}

// ---------------- fused score+softmax+aggregate -------------------------------
// q: bf16 [N,512] (carries /(16*sqrt(d))); kv8: fp8 e4m3 [N, k(512)|v(512)] (x16)
__global__ __launch_bounds__(256) void k_fsa(const int* __restrict__ offsets,
                                             const int* __restrict__ ssrc,
                                             const unsigned short* __restrict__ qb,
                                             const unsigned char* __restrict__ kv8,
                                             unsigned short* __restrict__ attn) {
    __shared__ float sacc[4][512];
    __shared__ float sden[4];
    int n = blockIdx.x, tid = threadIdx.x, wv = tid >> 6, ln = tid & 63;
    int beg = offsets[n], end = offsets[n + 1];
    union { short8 v; unsigned short u[8]; } qu;
    qu.v = *(const short8*)(qb + (size_t)n * 512 + ln * 8);
    float2v qf2[4];
#pragma unroll
    for (int j = 0; j < 4; j++) {
        qf2[j].x = bf2f(qu.u[2 * j]);
        qf2[j].y = bf2f(qu.u[2 * j + 1]);
    }
    float2v av2[4] = {{0,0},{0,0},{0,0},{0,0}};
    float den = 0.f;
    int i = beg + wv * 2;
    for (; i + 1 < end; i += 8) {
        const unsigned char* p0 = kv8 + (size_t)ssrc[i] * 1024 + ln * 8;
        const unsigned char* p1 = kv8 + (size_t)ssrc[i + 1] * 1024 + ln * 8;
        uint2 kd0 = *(const uint2*)p0;
        uint2 kd1 = *(const uint2*)p1;
        float2v a0 = {0, 0}, a1 = {0, 0};
        float2v p;
        p = __builtin_amdgcn_cvt_pk_f32_fp8(kd0.x, false); a0 += qf2[0] * p;
        p = __builtin_amdgcn_cvt_pk_f32_fp8(kd0.x, true);  a0 += qf2[1] * p;
        p = __builtin_amdgcn_cvt_pk_f32_fp8(kd0.y, false); a0 += qf2[2] * p;
        p = __builtin_amdgcn_cvt_pk_f32_fp8(kd0.y, true);  a0 += qf2[3] * p;
        p = __builtin_amdgcn_cvt_pk_f32_fp8(kd1.x, false); a1 += qf2[0] * p;
        p = __builtin_amdgcn_cvt_pk_f32_fp8(kd1.x, true);  a1 += qf2[1] * p;
        p = __builtin_amdgcn_cvt_pk_f32_fp8(kd1.y, false); a1 += qf2[2] * p;
        p = __builtin_amdgcn_cvt_pk_f32_fp8(kd1.y, true);  a1 += qf2[3] * p;
        float d0 = a0.x + a0.y, d1 = a1.x + a1.y;
#pragma unroll
        for (int off = 32; off >= 1; off >>= 1) {
            d0 += __shfl_xor(d0, off, 64);
            d1 += __shfl_xor(d1, off, 64);
        }
        float w0 = __expf(d0), w1 = __expf(d1);
        den += w0 + w1;
        uint2 vd0 = *(const uint2*)(p0 + 512);
        uint2 vd1 = *(const uint2*)(p1 + 512);
        float2v w20 = {w0, w0}, w21 = {w1, w1};
        p = __builtin_amdgcn_cvt_pk_f32_fp8(vd0.x, false); av2[0] += w20 * p;
        p = __builtin_amdgcn_cvt_pk_f32_fp8(vd0.x, true);  av2[1] += w20 * p;
        p = __builtin_amdgcn_cvt_pk_f32_fp8(vd0.y, false); av2[2] += w20 * p;
        p = __builtin_amdgcn_cvt_pk_f32_fp8(vd0.y, true);  av2[3] += w20 * p;
        p = __builtin_amdgcn_cvt_pk_f32_fp8(vd1.x, false); av2[0] += w21 * p;
        p = __builtin_amdgcn_cvt_pk_f32_fp8(vd1.x, true);  av2[1] += w21 * p;
        p = __builtin_amdgcn_cvt_pk_f32_fp8(vd1.y, false); av2[2] += w21 * p;
        p = __builtin_amdgcn_cvt_pk_f32_fp8(vd1.y, true);  av2[3] += w21 * p;
    }
    if (i < end) {
        const unsigned char* p0 = kv8 + (size_t)ssrc[i] * 1024 + ln * 8;
        uint2 kd0 = *(const uint2*)p0;
        float2v a0 = {0, 0};
        float2v p;
        p = __builtin_amdgcn_cvt_pk_f32_fp8(kd0.x, false); a0 += qf2[0] * p;
        p = __builtin_amdgcn_cvt_pk_f32_fp8(kd0.x, true);  a0 += qf2[1] * p;
        p = __builtin_amdgcn_cvt_pk_f32_fp8(kd0.y, false); a0 += qf2[2] * p;
        p = __builtin_amdgcn_cvt_pk_f32_fp8(kd0.y, true);  a0 += qf2[3] * p;
        float d0 = a0.x + a0.y;
#pragma unroll
        for (int off = 32; off >= 1; off >>= 1) d0 += __shfl_xor(d0, off, 64);
        float w0 = __expf(d0);
        den += w0;
        uint2 vd0 = *(const uint2*)(p0 + 512);
        float2v w20 = {w0, w0};
        p = __builtin_amdgcn_cvt_pk_f32_fp8(vd0.x, false); av2[0] += w20 * p;
        p = __builtin_amdgcn_cvt_pk_f32_fp8(vd0.x, true);  av2[1] += w20 * p;
        p = __builtin_amdgcn_cvt_pk_f32_fp8(vd0.y, false); av2[2] += w20 * p;
        p = __builtin_amdgcn_cvt_pk_f32_fp8(vd0.y, true);  av2[3] += w20 * p;
    }
    floatx4 s0v = {av2[0].x, av2[0].y, av2[1].x, av2[1].y};
    floatx4 s1v = {av2[2].x, av2[2].y, av2[3].x, av2[3].y};
    *(floatx4*)&sacc[wv][ln * 8]     = s0v;
    *(floatx4*)&sacc[wv][ln * 8 + 4] = s1v;
    if (ln == 0) sden[wv] = den;
    __syncthreads();
    // 0.0625 undoes the x16 fold on v
    float inv = 0.0625f / (sden[0] + sden[1] + sden[2] + sden[3]);
    int c = tid * 2;
    float t0 = sacc[0][c] + sacc[1][c] + sacc[2][c] + sacc[3][c];
    float t1 = sacc[0][c + 1] + sacc[1][c + 1] + sacc[2][c + 1] + sacc[3][c + 1];
    attn[(size_t)n * 512 + c]     = f2bf(t0 * inv);
    attn[(size_t)n * 512 + c + 1] = f2bf(t1 * inv);
}

// ---------------- expmap0 in place --------------------------------------------
__global__ __launch_bounds__(64) void k_expmap(float* h) {
    int row = blockIdx.x, lane = threadIdx.x;
    floatx4* hp = (floatx4*)(h + (size_t)row * DIMK + lane * 8);
    floatx4 h0 = hp[0], h1 = hp[1];
    float ss = 0.f;
#pragma unroll
    for (int i = 0; i < 4; i++) { ss += h0[i] * h0[i]; ss += h1[i] * h1[i]; }
#pragma unroll
    for (int off = 32; off >= 1; off >>= 1) ss += __shfl_xor(ss, off, 64);
    float n  = sqrtf(ss);
    float nc = fmaxf(n, 1e-7f);
    float fac = tanhf(nc) / nc;
#pragma unroll
    for (int i = 0; i < 4; i++) { h0[i] *= fac; h1[i] *= fac; }
    hp[0] = h0; hp[1] = h1;
}

extern "C" void kernel_launch(void* const* d_in, const int* in_sizes, int n_in,
                              void* d_out, int out_size, void* d_ws, size_t ws_size,
                              hipStream_t stream) {
    const float* x  = (const float*)d_in[0];
    const int* src  = (const int*)d_in[1];
    const int* dst  = (const int*)d_in[2];
    const float* Wq = (const float*)d_in[3];
    const float* bq = (const float*)d_in[4];
    const float* Wk = (const float*)d_in[5];
    const float* bk = (const float*)d_in[6];
    const float* Wv = (const float*)d_in[7];
    const float* bv = (const float*)d_in[8];
    const float* Wo = (const float*)d_in[9];
    const float* bo = (const float*)d_in[10];
    float* out = (float*)d_out;

    char* ws = (char*)d_ws;
    const size_t RB = (size_t)NND * DIMK * 2;      // 20.48 MB bf16 [N,512]
    const size_t KVB = (size_t)NND * 1024;         // 20.48 MB fp8 [N, k|v]
    const size_t WB = (size_t)DIMK * DIMK * 2;
    unsigned short* t    = (unsigned short*)(ws);              // reused as attn
    unsigned short* qb   = (unsigned short*)(ws + RB);
    unsigned char*  kv8  = (unsigned char*)(ws + 2 * RB);
    unsigned short* Wqkv = (unsigned short*)(ws + 2 * RB + KVB);
    unsigned short* Wob  = (unsigned short*)(ws + 2 * RB + KVB + 3 * WB);
    float* biasf         = (float*)(ws + 2 * RB + KVB + 4 * WB);
    char* p = ws + 2 * RB + KVB + 4 * WB + 1536 * 4;
    int* ssrc    = (int*)p;
    int* counts  = ssrc + NE;
    int* offsets = counts + NND;
    int* pos     = offsets + NND + 2;
    unsigned short* attn = t;

    hipMemsetAsync(counts, 0, (size_t)NND * 4, stream);

    const float scale_q = 0.04419417382415922f / 16.0f;   // (1/sqrt(512)) / 16
    k_pre<<<7280, 256, 0, stream>>>(x, Wq, Wk, Wv, Wo, bq, bk, bv, dst, counts,
                                    t, Wqkv, Wob, biasf, scale_q);

    k_scan<<<1, 1024, 0, stream>>>(counts, offsets, pos);
    k_scatter<<<(NE + 255) / 256, 256, 0, stream>>>(dst, src, pos, ssrc);

    // fused q/k/v GEMM: [20000 x 1536] -> qb bf16 / kv8 fp8 (k|v interleaved)
    k_gemm<<<8 * 20 * 12, 256, 0, stream>>>(t, Wqkv, biasf, qb, kv8, nullptr,
                                            NND, 157, 12, 1536);

    k_fsa<<<NND, 256, 0, stream>>>(offsets, ssrc, qb, kv8, attn);

    // output projection (fp32 into d_out), expmap in place
    k_gemm<<<8 * 20 * 4, 256, 0, stream>>>(attn, Wob, bo, nullptr, nullptr, out,
                                           NND, 157, 4, 512);
    k_expmap<<<NND, 64, 0, stream>>>(out);
}